// Round 4
// baseline (1352.266 us; speedup 1.0000x reference)
//
#include <hip/hip_runtime.h>
#include <hip/hip_fp16.h>

#define B_ 16384
#define T_ 128
#define E_ 32
#define H_ 128
#define G3_ 384
#define V_ 30001
#define D_ 128
#define C_ 3

typedef _Float16 f16;
typedef f16 f16x8 __attribute__((ext_vector_type(8)));
typedef float f32x4 __attribute__((ext_vector_type(4)));

// ---- LDS layout (bytes), 256-thread block, 16 batch rows ----
#define HPITCH   272                 // h row pitch: 128 f16 used, pad to 17*16B
#define H0_OFF   0                   // h buffer 0: 16*272 = 4352
#define H1_OFF   4352                // h buffer 1
#define TOK_OFF  8704                // stok u16 [16][136] = 4352 B
#define DBUF_OFF 13056               // head dbuf f32 [16][132] = 8448 B
#define LDS_TOTAL 21504

__device__ __forceinline__ float frcp_(float x) { return __builtin_amdgcn_rcpf(x); }
// inf-safe, clamp-free: sigmoid(+-inf)=1/0, tanh(+-inf)=+-1
__device__ __forceinline__ float fsigm_(float x) {
    return frcp_(1.f + __expf(-x));
}
__device__ __forceinline__ float ftanh_(float x) {
    return fmaf(-2.f, frcp_(1.f + __expf(2.f * x)), 1.f);
}

// ---------------- Kernel 1: embW16[v][g] = f16(emb[v][:] @ W[:][g] + b0[g]) ----------------
#define K1_ROWS 8
__global__ __launch_bounds__(384) void embw_kernel(
    const float* __restrict__ emb,   // [V][32]
    const float* __restrict__ W,     // [32][384]
    const float* __restrict__ b_in,  // [384] (= b row 0)
    f16* __restrict__ embW)          // [V][384] f16
{
    __shared__ float sW[E_][G3_];
    __shared__ float sE[K1_ROWS][E_];
    const int g = threadIdx.x;
    #pragma unroll
    for (int e = 0; e < E_; ++e) sW[e][g] = W[e * G3_ + g];
    const int v0 = blockIdx.x * K1_ROWS;
    for (int idx = g; idx < K1_ROWS * E_; idx += 384) {
        int rr = idx >> 5, ee = idx & 31;
        int v = v0 + rr;
        sE[rr][ee] = (v < V_) ? emb[v * E_ + ee] : 0.f;
    }
    __syncthreads();
    const float bg = b_in[g];
    #pragma unroll
    for (int rr = 0; rr < K1_ROWS; ++rr) {
        int v = v0 + rr;
        if (v >= V_) break;
        float acc = bg;
        #pragma unroll
        for (int e = 0; e < E_; ++e) acc = fmaf(sE[rr][e], sW[e][g], acc);
        embW[(size_t)v * G3_ + g] = (f16)acc;
    }
}

// ---------------- Kernel 2: GRU with U persistent in VGPRs ----------------
// 1024 blocks x 256 threads (4 waves). Block owns 16 batch rows; wave w owns
// h-cols [32w, 32w+32). U slice (24 f16x8 = 96 VGPR) persistent in registers.
// h double-buffered in LDS; one __syncthreads per step.
// MFMA 16x16x32 f16 layouts (verified rounds 2-3):
//   A: lane l holds A[l&15][(l>>4)*8 + j]
//   B: lane l holds B[(l>>4)*8 + j][l&15]
//   C/D: lane l, reg i -> row=(l>>4)*4+i, col=l&15
__global__ __launch_bounds__(256, 4) void gru_mfma_kernel(
    const int*   __restrict__ tokens,  // [B][T]
    const f16*   __restrict__ embW,    // [V][384] f16 (includes input bias b0)
    const float* __restrict__ U,       // [128][384]
    const float* __restrict__ b,       // [2][384]
    const float* __restrict__ W1,      // [128][128]
    const float* __restrict__ b1,      // [128]
    const float* __restrict__ Wout,    // [128][3]
    const float* __restrict__ bout,    // [3]
    float* __restrict__ out)           // [B][3]
{
    __shared__ char lds[LDS_TOTAL];
    const int tid = threadIdx.x;
    const int w   = tid >> 6;       // wave = h-col group, 0..3
    const int l   = tid & 63;
    const int cl  = l & 15;
    const int q   = l >> 4;         // 0..3
    const int R0  = blockIdx.x * 16;

    // ---- stage tokens as u16 (max token 30000 < 65536) ----
    for (int idx = tid; idx < 16 * T_; idx += 256) {
        int r = idx >> 7, t = idx & 127;
        *(unsigned short*)(&lds[TOK_OFF + r * HPITCH + t * 2]) =
            (unsigned short)tokens[(size_t)(R0 + r) * T_ + t];
    }
    // ---- zero h buffer 0 ----
    for (int idx = tid; idx < H1_OFF / 4; idx += 256)
        ((float*)lds)[idx] = 0.f;

    // ---- persistent U fragments (one-time strided global read, L2-hot) ----
    // Bf[g][gate][kt]: lane holds U[kt*32+q*8+j][gate*128 + w*32 + g*16 + cl]
    f16x8 Bf[2][3][4];
    #pragma unroll
    for (int g = 0; g < 2; ++g)
        #pragma unroll
        for (int gt = 0; gt < 3; ++gt) {
            const int n = gt * 128 + w * 32 + g * 16 + cl;
            #pragma unroll
            for (int kt = 0; kt < 4; ++kt) {
                const int k0 = kt * 32 + q * 8;
                f16x8 fr;
                #pragma unroll
                for (int j = 0; j < 8; ++j)
                    fr[j] = (f16)U[(size_t)(k0 + j) * G3_ + n];
                Bf[g][gt][kt] = fr;
            }
        }

    // recurrent biases for this lane's 2 col-tiles
    float bz[2], br[2], bh[2];
    #pragma unroll
    for (int g = 0; g < 2; ++g) {
        const int col = w * 32 + g * 16 + cl;
        bz[g] = b[G3_ + col];
        br[g] = b[G3_ + 128 + col];
        bh[g] = b[G3_ + 256 + col];
    }

    float hreg[2][4];   // [g][i]
    #pragma unroll
    for (int g = 0; g < 2; ++g)
        #pragma unroll
        for (int i = 0; i < 4; ++i) hreg[g][i] = 0.f;

    __syncthreads();

    int cur = 0;
    for (int t = 0; t < T_; ++t) {
        const char* hb = &lds[cur ? H1_OFF : H0_OFF];
        char*       hn = &lds[cur ? H0_OFF : H1_OFF];

        // tokens for this lane's 4 gate rows (rows 4q+i)
        int tk[4];
        #pragma unroll
        for (int i = 0; i < 4; ++i)
            tk[i] = *(const unsigned short*)
                (&lds[TOK_OFF + (4 * q + i) * HPITCH + t * 2]);

        // gather xg (f16 table; hidden under MFMAs by the scheduler/other waves)
        float xz[2][4], xr[2][4], xh[2][4];
        #pragma unroll
        for (int i = 0; i < 4; ++i) {
            const f16* xp = embW + (size_t)tk[i] * G3_ + w * 32 + cl;
            #pragma unroll
            for (int g = 0; g < 2; ++g) {
                xz[g][i] = (float)xp[g * 16];
                xr[g][i] = (float)xp[128 + g * 16];
                xh[g][i] = (float)xp[256 + g * 16];
            }
        }

        // A-fragments: g-invariant, load once per step
        f16x8 af[4];
        #pragma unroll
        for (int kt = 0; kt < 4; ++kt)
            af[kt] = *(const f16x8*)(hb + cl * HPITCH + kt * 64 + q * 16);

        #pragma unroll
        for (int g = 0; g < 2; ++g) {
            f32x4 accz = {bz[g], bz[g], bz[g], bz[g]};
            f32x4 accr = {br[g], br[g], br[g], br[g]};
            f32x4 acch = {bh[g], bh[g], bh[g], bh[g]};
            #pragma unroll
            for (int kt = 0; kt < 4; ++kt) {
                accz = __builtin_amdgcn_mfma_f32_16x16x32_f16(af[kt], Bf[g][0][kt], accz, 0, 0, 0);
                accr = __builtin_amdgcn_mfma_f32_16x16x32_f16(af[kt], Bf[g][1][kt], accr, 0, 0, 0);
                acch = __builtin_amdgcn_mfma_f32_16x16x32_f16(af[kt], Bf[g][2][kt], acch, 0, 0, 0);
            }
            // gates + state update for this col-tile
            #pragma unroll
            for (int i = 0; i < 4; ++i) {
                const float z  = fsigm_(xz[g][i] + accz[i]);
                const float r  = fsigm_(xr[g][i] + accr[i]);
                const float hh = ftanh_(fmaf(r, acch[i], xh[g][i]));
                const float hv = hreg[g][i];
                float nv = hh + z * (hv - hh);
                nv = (tk[i] != 0) ? nv : hv;
                hreg[g][i] = nv;
                *(f16*)(hn + (4 * q + i) * HPITCH
                           + (w * 32 + g * 16 + cl) * 2) = (f16)nv;
            }
        }
        __syncthreads();
        cur ^= 1;
    }
    // T_=128 even -> final h is in buffer 0

    // ---- head: d = swish(h @ W1 + b1) ----
    f16x8 Wf[2][4];
    #pragma unroll
    for (int ct = 0; ct < 2; ++ct) {
        const int n = w * 32 + ct * 16 + cl;
        #pragma unroll
        for (int kt = 0; kt < 4; ++kt) {
            const int k0 = kt * 32 + q * 8;
            f16x8 fr;
            #pragma unroll
            for (int j = 0; j < 8; ++j)
                fr[j] = (f16)W1[(size_t)(k0 + j) * D_ + n];
            Wf[ct][kt] = fr;
        }
    }
    {
        const char* hb = &lds[H0_OFF];
        f16x8 af[4];
        #pragma unroll
        for (int kt = 0; kt < 4; ++kt)
            af[kt] = *(const f16x8*)(hb + cl * HPITCH + kt * 64 + q * 16);
        f32x4 dacc[2];
        #pragma unroll
        for (int ct = 0; ct < 2; ++ct) {
            const float bd = b1[w * 32 + ct * 16 + cl];
            dacc[ct] = (f32x4){bd, bd, bd, bd};
        }
        #pragma unroll
        for (int kt = 0; kt < 4; ++kt) {
            dacc[0] = __builtin_amdgcn_mfma_f32_16x16x32_f16(af[kt], Wf[0][kt], dacc[0], 0, 0, 0);
            dacc[1] = __builtin_amdgcn_mfma_f32_16x16x32_f16(af[kt], Wf[1][kt], dacc[1], 0, 0, 0);
        }
        #pragma unroll
        for (int ct = 0; ct < 2; ++ct)
            #pragma unroll
            for (int i = 0; i < 4; ++i) {
                const float v = dacc[ct][i];
                *(float*)(&lds[DBUF_OFF + (4 * q + i) * 528
                               + (w * 32 + ct * 16 + cl) * 4]) = v * fsigm_(v);
            }
    }
    __syncthreads();

    // ---- logits + softmax: wave 0, 48 lanes = 16 rows x 3 classes ----
    if (w == 0 && l < 48) {
        const int row = l & 15, ci = l >> 4;
        float acc = bout[ci];
        #pragma unroll 4
        for (int k = 0; k < D_; ++k)
            acc = fmaf(*(const float*)(&lds[DBUF_OFF + row * 528 + k * 4]),
                       Wout[k * 3 + ci], acc);
        const float v0 = __shfl(acc, row);
        const float v1 = __shfl(acc, row + 16);
        const float v2 = __shfl(acc, row + 32);
        const float mx = fmaxf(v0, fmaxf(v1, v2));
        const float e0 = __expf(v0 - mx), e1 = __expf(v1 - mx), e2 = __expf(v2 - mx);
        const float inv = frcp_(e0 + e1 + e2);
        const float mine = (ci == 0) ? e0 : (ci == 1) ? e1 : e2;
        out[(size_t)(R0 + row) * 3 + ci] = mine * inv;
    }
}

extern "C" void kernel_launch(void* const* d_in, const int* in_sizes, int n_in,
                              void* d_out, int out_size, void* d_ws, size_t ws_size,
                              hipStream_t stream) {
    (void)in_sizes; (void)n_in; (void)out_size; (void)ws_size;
    const int*   tokens = (const int*)d_in[0];
    const float* emb    = (const float*)d_in[1];
    const float* W      = (const float*)d_in[2];
    const float* U      = (const float*)d_in[3];
    const float* b      = (const float*)d_in[4];
    const float* W1     = (const float*)d_in[5];
    const float* b1     = (const float*)d_in[6];
    const float* Wout   = (const float*)d_in[7];
    const float* bout   = (const float*)d_in[8];
    float* out  = (float*)d_out;
    f16*   embW = (f16*)d_ws;   // [V][384] f16 = 23 MB scratch

    hipLaunchKernelGGL(embw_kernel, dim3((V_ + K1_ROWS - 1) / K1_ROWS), dim3(384), 0, stream,
                       emb, W, b, embW);
    hipLaunchKernelGGL(gru_mfma_kernel, dim3(B_ / 16), dim3(256), 0, stream,
                       tokens, embW, U, b, W1, b1, Wout, bout, out);
}

// Round 5
// 424.776 us; speedup vs baseline: 3.1835x; 3.1835x over previous
//
#include <hip/hip_runtime.h>
#include <hip/hip_fp16.h>

#define B_ 16384
#define T_ 128
#define E_ 32
#define H_ 128
#define G3_ 384
#define V_ 30001
#define D_ 128
#define C_ 3

typedef _Float16 f16;
typedef f16 f16x4 __attribute__((ext_vector_type(4)));
typedef f16 f16x8 __attribute__((ext_vector_type(8)));
typedef float f32x4 __attribute__((ext_vector_type(4)));

// ---- LDS layout (bytes), 512-thread block, 16 batch rows ----
#define HPITCH   272                 // h row pitch: 128 f16 used, pad to 17*16B
#define H0_OFF   0                   // h buffer 0: 16*272 = 4352
#define H1_OFF   4352                // h buffer 1
#define TOK_OFF  8704                // stok u16 [16][136] = 4352 B
#define DBUF_OFF 13056               // head dbuf f32 [16][132] = 8448 B
#define LDS_TOTAL 21504

__device__ __forceinline__ float frcp_(float x) { return __builtin_amdgcn_rcpf(x); }
// inf-safe, clamp-free: sigmoid(+-inf)=1/0, tanh(+-inf)=+-1
__device__ __forceinline__ float fsigm_(float x) {
    return frcp_(1.f + __expf(-x));
}
__device__ __forceinline__ float ftanh_(float x) {
    return fmaf(-2.f, frcp_(1.f + __expf(2.f * x)), 1.f);
}

// ---------------- Kernel 1: packed table ----------------
// embW_p[v][c][slot] f16, slot: 0=z,1=r,2=h,3=pad; c in [0,128).
// value(v,c,slot) = emb[v][:] @ W[:][slot*128+c] + b0[slot*128+c]
#define K1_ROWS 8
__global__ __launch_bounds__(384) void embw_kernel(
    const float* __restrict__ emb,   // [V][32]
    const float* __restrict__ W,     // [32][384]
    const float* __restrict__ b_in,  // [384] (= b row 0)
    f16* __restrict__ embW)          // [V][128][4] f16
{
    __shared__ float sW[E_][G3_];
    __shared__ float sE[K1_ROWS][E_];
    const int g = threadIdx.x;           // 0..383 (= slot*128 + c)
    #pragma unroll
    for (int e = 0; e < E_; ++e) sW[e][g] = W[e * G3_ + g];
    const int v0 = blockIdx.x * K1_ROWS;
    for (int idx = g; idx < K1_ROWS * E_; idx += 384) {
        int rr = idx >> 5, ee = idx & 31;
        int v = v0 + rr;
        sE[rr][ee] = (v < V_) ? emb[v * E_ + ee] : 0.f;
    }
    __syncthreads();
    const float bg = b_in[g];
    const int c = g & 127, slot = g >> 7;
    #pragma unroll
    for (int rr = 0; rr < K1_ROWS; ++rr) {
        int v = v0 + rr;
        if (v >= V_) break;
        float acc = bg;
        #pragma unroll
        for (int e = 0; e < E_; ++e) acc = fmaf(sE[rr][e], sW[e][g], acc);
        embW[(size_t)v * 512 + c * 4 + slot] = (f16)acc;
    }
}

// ---------------- Kernel 2: GRU, 8 waves x 16 cols, U persistent in VGPRs ----------------
// 1024 blocks x 512 threads (8 waves). Block owns 16 batch rows; wave w owns
// h-cols [16w, 16w+16). U slice = 12 f16x8 frags = 48 VGPR -> total live ~115,
// fits the 128-VGPR step => 2 blocks/CU = 4 waves/SIMD.
// MFMA 16x16x32 f16 layouts (verified rounds 2-4):
//   A: lane l holds A[l&15][(l>>4)*8 + j]
//   B: lane l holds B[(l>>4)*8 + j][l&15]
//   C/D: lane l, reg i -> row=(l>>4)*4+i, col=l&15
__global__ __launch_bounds__(512, 4) void gru_mfma_kernel(
    const int*   __restrict__ tokens,  // [B][T]
    const f16*   __restrict__ embW,    // [V][128][4] f16 packed (includes b0)
    const float* __restrict__ U,       // [128][384]
    const float* __restrict__ b,       // [2][384]
    const float* __restrict__ W1,      // [128][128]
    const float* __restrict__ b1,      // [128]
    const float* __restrict__ Wout,    // [128][3]
    const float* __restrict__ bout,    // [3]
    float* __restrict__ out)           // [B][3]
{
    __shared__ char lds[LDS_TOTAL];
    const int tid = threadIdx.x;
    const int w   = tid >> 6;       // wave = 16-col group, 0..7
    const int l   = tid & 63;
    const int cl  = l & 15;
    const int q   = l >> 4;         // 0..3
    const int R0  = blockIdx.x * 16;
    const int col = w * 16 + cl;    // this lane's h column

    // ---- stage tokens as u16 (max token 30000 < 65536) ----
    for (int idx = tid; idx < 16 * T_; idx += 512) {
        int r = idx >> 7, t = idx & 127;
        *(unsigned short*)(&lds[TOK_OFF + r * HPITCH + t * 2]) =
            (unsigned short)tokens[(size_t)(R0 + r) * T_ + t];
    }
    // ---- zero h buffer 0 ----
    for (int idx = tid; idx < H1_OFF / 4; idx += 512)
        ((float*)lds)[idx] = 0.f;

    // ---- persistent U fragments (one-time strided global read) ----
    // Bf[gate][kt]: lane holds U[kt*32 + q*8 + j][gate*128 + col]
    f16x8 Bf[3][4];
    #pragma unroll
    for (int gt = 0; gt < 3; ++gt) {
        const int n = gt * 128 + col;
        #pragma unroll
        for (int kt = 0; kt < 4; ++kt) {
            const int k0 = kt * 32 + q * 8;
            f16x8 fr;
            #pragma unroll
            for (int j = 0; j < 8; ++j)
                fr[j] = (f16)U[(size_t)(k0 + j) * G3_ + n];
            Bf[gt][kt] = fr;
        }
    }

    // recurrent biases for this lane's column
    const float bz = b[G3_ + col];
    const float br = b[G3_ + 128 + col];
    const float bh = b[G3_ + 256 + col];

    float hreg[4];
    #pragma unroll
    for (int i = 0; i < 4; ++i) hreg[i] = 0.f;

    __syncthreads();

    int cur = 0;
    for (int t = 0; t < T_; ++t) {
        const char* hb = &lds[cur ? H1_OFF : H0_OFF];
        char*       hn = &lds[cur ? H0_OFF : H1_OFF];

        // tokens + packed xg gather for this lane's 4 rows (rows 4q+i)
        int tk[4];
        f16x4 xv[4];
        #pragma unroll
        for (int i = 0; i < 4; ++i) {
            tk[i] = *(const unsigned short*)
                (&lds[TOK_OFF + (4 * q + i) * HPITCH + t * 2]);
            xv[i] = *(const f16x4*)(embW + (size_t)tk[i] * 512 + col * 4);
        }

        // A-fragments: h at step t
        f16x8 af[4];
        #pragma unroll
        for (int kt = 0; kt < 4; ++kt)
            af[kt] = *(const f16x8*)(hb + cl * HPITCH + kt * 64 + q * 16);

        f32x4 accz = {bz, bz, bz, bz};
        f32x4 accr = {br, br, br, br};
        f32x4 acch = {bh, bh, bh, bh};
        #pragma unroll
        for (int kt = 0; kt < 4; ++kt) {
            accz = __builtin_amdgcn_mfma_f32_16x16x32_f16(af[kt], Bf[0][kt], accz, 0, 0, 0);
            accr = __builtin_amdgcn_mfma_f32_16x16x32_f16(af[kt], Bf[1][kt], accr, 0, 0, 0);
            acch = __builtin_amdgcn_mfma_f32_16x16x32_f16(af[kt], Bf[2][kt], acch, 0, 0, 0);
        }

        // gates + state update (element (row=4q+i, col))
        #pragma unroll
        for (int i = 0; i < 4; ++i) {
            const float z  = fsigm_((float)xv[i][0] + accz[i]);
            const float r  = fsigm_((float)xv[i][1] + accr[i]);
            const float hh = ftanh_(fmaf(r, acch[i], (float)xv[i][2]));
            const float hv = hreg[i];
            float nv = hh + z * (hv - hh);
            nv = (tk[i] != 0) ? nv : hv;
            hreg[i] = nv;
            *(f16*)(hn + (4 * q + i) * HPITCH + col * 2) = (f16)nv;
        }
        __syncthreads();
        cur ^= 1;
    }
    // T_=128 even -> final h is in buffer 0

    // ---- head: d = swish(h @ W1 + b1), one 16-col tile per wave ----
    {
        f16x8 Wf[4];
        #pragma unroll
        for (int kt = 0; kt < 4; ++kt) {
            const int k0 = kt * 32 + q * 8;
            f16x8 fr;
            #pragma unroll
            for (int j = 0; j < 8; ++j)
                fr[j] = (f16)W1[(size_t)(k0 + j) * D_ + col];
            Wf[kt] = fr;
        }
        const char* hb = &lds[H0_OFF];
        f16x8 af[4];
        #pragma unroll
        for (int kt = 0; kt < 4; ++kt)
            af[kt] = *(const f16x8*)(hb + cl * HPITCH + kt * 64 + q * 16);
        const float bd = b1[col];
        f32x4 dacc = {bd, bd, bd, bd};
        #pragma unroll
        for (int kt = 0; kt < 4; ++kt)
            dacc = __builtin_amdgcn_mfma_f32_16x16x32_f16(af[kt], Wf[kt], dacc, 0, 0, 0);
        #pragma unroll
        for (int i = 0; i < 4; ++i) {
            const float v = dacc[i];
            *(float*)(&lds[DBUF_OFF + (4 * q + i) * 528 + col * 4]) = v * fsigm_(v);
        }
    }
    __syncthreads();

    // ---- logits + softmax: wave 0, 48 lanes = 16 rows x 3 classes ----
    if (w == 0 && l < 48) {
        const int row = l & 15, ci = l >> 4;
        float acc = bout[ci];
        #pragma unroll 4
        for (int k = 0; k < D_; ++k)
            acc = fmaf(*(const float*)(&lds[DBUF_OFF + row * 528 + k * 4]),
                       Wout[k * 3 + ci], acc);
        const float v0 = __shfl(acc, row);
        const float v1 = __shfl(acc, row + 16);
        const float v2 = __shfl(acc, row + 32);
        const float mx = fmaxf(v0, fmaxf(v1, v2));
        const float e0 = __expf(v0 - mx), e1 = __expf(v1 - mx), e2 = __expf(v2 - mx);
        const float inv = frcp_(e0 + e1 + e2);
        const float mine = (ci == 0) ? e0 : (ci == 1) ? e1 : e2;
        out[(size_t)(R0 + row) * 3 + ci] = mine * inv;
    }
}

extern "C" void kernel_launch(void* const* d_in, const int* in_sizes, int n_in,
                              void* d_out, int out_size, void* d_ws, size_t ws_size,
                              hipStream_t stream) {
    (void)in_sizes; (void)n_in; (void)out_size; (void)ws_size;
    const int*   tokens = (const int*)d_in[0];
    const float* emb    = (const float*)d_in[1];
    const float* W      = (const float*)d_in[2];
    const float* U      = (const float*)d_in[3];
    const float* b      = (const float*)d_in[4];
    const float* W1     = (const float*)d_in[5];
    const float* b1     = (const float*)d_in[6];
    const float* Wout   = (const float*)d_in[7];
    const float* bout   = (const float*)d_in[8];
    float* out  = (float*)d_out;
    f16*   embW = (f16*)d_ws;   // [V][128][4] f16 = 30.7 MB scratch

    hipLaunchKernelGGL(embw_kernel, dim3((V_ + K1_ROWS - 1) / K1_ROWS), dim3(384), 0, stream,
                       emb, W, b, embW);
    hipLaunchKernelGGL(gru_mfma_kernel, dim3(B_ / 16), dim3(512), 0, stream,
                       tokens, embW, U, b, W1, b1, Wout, bout, out);
}

// Round 6
// 375.663 us; speedup vs baseline: 3.5997x; 1.1307x over previous
//
#include <hip/hip_runtime.h>
#include <hip/hip_fp16.h>

#define B_ 16384
#define T_ 128
#define E_ 32
#define H_ 128
#define G3_ 384
#define V_ 30001
#define D_ 128
#define C_ 3

#define LOG2E 1.44269504088896340736f

typedef _Float16 f16;
typedef f16 f16x4 __attribute__((ext_vector_type(4)));
typedef f16 f16x8 __attribute__((ext_vector_type(8)));
typedef float f32x4 __attribute__((ext_vector_type(4)));
typedef unsigned int u32;
typedef u32 u32x4 __attribute__((ext_vector_type(4)));

// ---- LDS layout (bytes), 512-thread block, 16 batch rows ----
// h buffers: [16 rows][256 B], XOR-swizzled: byte(row,col) = row*256 + (col*2 ^ ((row&7)<<4))
#define H0_OFF   0
#define H1_OFF   4096
#define TOK_OFF  8192                // u32 byte-offsets, transposed [t=128][r=16]
#define DBUF_OFF 16384               // head dbuf f32 [16][132]
#define LDS_TOTAL 24832

__device__ __forceinline__ float frcp_(float x)  { return __builtin_amdgcn_rcpf(x); }
__device__ __forceinline__ float fexp2_(float x) { return __builtin_amdgcn_exp2f(x); }

// ---------------- Kernel 1: packed, PRE-SCALED table ----------------
// embW_p[v][c][slot] f16; slot 0=z,1=r (scaled by -log2e), 2=h (scaled by +2log2e), 3=pad.
// raw(v,c,slot) = emb[v][:] @ W[:][slot*128+c] + b0[slot*128+c]
#define K1_ROWS 8
__global__ __launch_bounds__(384) void embw_kernel(
    const float* __restrict__ emb,   // [V][32]
    const float* __restrict__ W,     // [32][384]
    const float* __restrict__ b_in,  // [384] (= b row 0)
    f16* __restrict__ embW)          // [V][128][4] f16
{
    __shared__ float sW[E_][G3_];
    __shared__ float sE[K1_ROWS][E_];
    const int g = threadIdx.x;           // 0..383 (= slot*128 + c)
    #pragma unroll
    for (int e = 0; e < E_; ++e) sW[e][g] = W[e * G3_ + g];
    const int v0 = blockIdx.x * K1_ROWS;
    for (int idx = g; idx < K1_ROWS * E_; idx += 384) {
        int rr = idx >> 5, ee = idx & 31;
        int v = v0 + rr;
        sE[rr][ee] = (v < V_) ? emb[v * E_ + ee] : 0.f;
    }
    __syncthreads();
    const float bg = b_in[g];
    const int c = g & 127, slot = g >> 7;
    const float sc = (slot == 2) ? (2.f * LOG2E) : (-LOG2E);
    #pragma unroll
    for (int rr = 0; rr < K1_ROWS; ++rr) {
        int v = v0 + rr;
        if (v >= V_) break;
        float acc = bg;
        #pragma unroll
        for (int e = 0; e < E_; ++e) acc = fmaf(sE[rr][e], sW[e][g], acc);
        embW[(size_t)v * 512 + c * 4 + slot] = (f16)(acc * sc);
    }
}

// ---------------- Kernel 2: GRU, 8 waves x 16 cols, U persistent in VGPRs ----------------
// 1024 blocks x 512 threads. Block owns 16 batch rows; wave w owns h-cols
// [16w,16w+16). U slice pre-scaled for exp2-direct gates. xg gathered with a
// 1-step software prefetch. h XOR-swizzled in LDS.
// MFMA 16x16x32 f16 layouts (verified rounds 2-5):
//   A: lane l holds A[l&15][(l>>4)*8 + j]
//   B: lane l holds B[(l>>4)*8 + j][l&15]
//   C/D: lane l, reg i -> row=(l>>4)*4+i, col=l&15
__global__ __launch_bounds__(512, 4) void gru_mfma_kernel(
    const int*   __restrict__ tokens,  // [B][T]
    const f16*   __restrict__ embW,    // [V][128][4] f16 packed, pre-scaled
    const float* __restrict__ U,       // [128][384]
    const float* __restrict__ b,       // [2][384]
    const float* __restrict__ W1,      // [128][128]
    const float* __restrict__ b1,      // [128]
    const float* __restrict__ Wout,    // [128][3]
    const float* __restrict__ bout,    // [3]
    float* __restrict__ out)           // [B][3]
{
    __shared__ char lds[LDS_TOTAL];
    const int tid = threadIdx.x;
    const int w   = tid >> 6;       // wave = 16-col group, 0..7
    const int l   = tid & 63;
    const int cl  = l & 15;
    const int q   = l >> 4;         // 0..3
    const int R0  = blockIdx.x * 16;
    const int col = w * 16 + cl;    // this lane's h column

    // ---- stage token BYTE OFFSETS, transposed [t][r] (tok*1024 = row stride in embW) ----
    for (int idx = tid; idx < 16 * T_; idx += 512) {
        int r = idx >> 7, t = idx & 127;
        u32 tok = (u32)tokens[(size_t)(R0 + r) * T_ + t];
        *(u32*)(&lds[TOK_OFF + t * 64 + r * 4]) = tok * 1024u;
    }
    // ---- zero h buffer 0 ----
    for (int idx = tid; idx < 1024; idx += 512)
        ((float*)(lds + H0_OFF))[idx] = 0.f;

    // ---- persistent U fragments, pre-scaled (one-time strided global read) ----
    // Bf[gate][kt]: lane holds sc(gate) * U[kt*32 + q*8 + j][gate*128 + col]
    f16x8 Bf[3][4];
    #pragma unroll
    for (int gt = 0; gt < 3; ++gt) {
        const float sc = (gt == 2) ? (2.f * LOG2E) : (-LOG2E);
        const int n = gt * 128 + col;
        #pragma unroll
        for (int kt = 0; kt < 4; ++kt) {
            const int k0 = kt * 32 + q * 8;
            f16x8 fr;
            #pragma unroll
            for (int j = 0; j < 8; ++j)
                fr[j] = (f16)(U[(size_t)(k0 + j) * G3_ + n] * sc);
            Bf[gt][kt] = fr;
        }
    }

    // pre-scaled recurrent biases (zeros in this problem, honored anyway)
    const float bz = -LOG2E * b[G3_ + col];
    const float br = -LOG2E * b[G3_ + 128 + col];
    const float bh = 2.f * LOG2E * b[G3_ + 256 + col];

    float hreg[4];
    #pragma unroll
    for (int i = 0; i < 4; ++i) hreg[i] = 0.f;

    __syncthreads();

    const char* embWb = (const char*)embW;
    const int col8 = col * 8;

    // prefetch t=0
    u32x4 offc = *(const u32x4*)(&lds[TOK_OFF + q * 16]);
    f16x4 xvc[4];
    #pragma unroll
    for (int i = 0; i < 4; ++i)
        xvc[i] = *(const f16x4*)(embWb + offc[i] + col8);

    int cur = 0;
    for (int t = 0; t < T_; ++t) {
        const char* hb = lds + (cur ? H1_OFF : H0_OFF);
        char*       hn = lds + (cur ? H0_OFF : H1_OFF);

        // ---- issue prefetch for t+1 (h-independent; lands during MFMAs) ----
        u32x4 offn = offc;
        f16x4 xvn[4];
        #pragma unroll
        for (int i = 0; i < 4; ++i) xvn[i] = xvc[i];
        if (t + 1 < T_) {
            offn = *(const u32x4*)(&lds[TOK_OFF + (t + 1) * 64 + q * 16]);
            #pragma unroll
            for (int i = 0; i < 4; ++i)
                xvn[i] = *(const f16x4*)(embWb + offn[i] + col8);
        }

        // ---- rec = h @ U (pre-scaled), swizzled A reads ----
        f32x4 accz = {bz, bz, bz, bz};
        f32x4 accr = {br, br, br, br};
        f32x4 acch = {bh, bh, bh, bh};
        #pragma unroll
        for (int kt = 0; kt < 4; ++kt) {
            const int chunk = (kt * 64 + q * 16) ^ ((cl & 7) << 4);
            const f16x8 af = *(const f16x8*)(hb + cl * 256 + chunk);
            accz = __builtin_amdgcn_mfma_f32_16x16x32_f16(af, Bf[0][kt], accz, 0, 0, 0);
            accr = __builtin_amdgcn_mfma_f32_16x16x32_f16(af, Bf[1][kt], accr, 0, 0, 0);
            acch = __builtin_amdgcn_mfma_f32_16x16x32_f16(af, Bf[2][kt], acch, 0, 0, 0);
        }

        // ---- gates (exp2-direct) + state update ----
        #pragma unroll
        for (int i = 0; i < 4; ++i) {
            const float z  = frcp_(1.f + fexp2_((float)xvc[i][0] + accz[i]));
            const float r  = frcp_(1.f + fexp2_((float)xvc[i][1] + accr[i]));
            const float hh = fmaf(-2.f, frcp_(1.f + fexp2_(fmaf(r, acch[i], (float)xvc[i][2]))), 1.f);
            const float hv = hreg[i];
            float nv = fmaf(z, hv - hh, hh);
            nv = (offc[i] != 0u) ? nv : hv;
            hreg[i] = nv;
            const int row = 4 * q + i;
            *(f16*)(hn + row * 256 + ((col * 2) ^ ((row & 7) << 4))) = (f16)nv;
        }
        __syncthreads();
        cur ^= 1;
        offc = offn;
        #pragma unroll
        for (int i = 0; i < 4; ++i) xvc[i] = xvn[i];
    }
    // T_=128 even -> final h is in buffer 0

    // ---- head: d = swish(h @ W1 + b1), one 16-col tile per wave ----
    {
        f16x8 Wf[4];
        #pragma unroll
        for (int kt = 0; kt < 4; ++kt) {
            const int k0 = kt * 32 + q * 8;
            f16x8 fr;
            #pragma unroll
            for (int j = 0; j < 8; ++j)
                fr[j] = (f16)W1[(size_t)(k0 + j) * D_ + col];
            Wf[kt] = fr;
        }
        const char* hb = lds + H0_OFF;
        const float bd = b1[col];
        f32x4 dacc = {bd, bd, bd, bd};
        #pragma unroll
        for (int kt = 0; kt < 4; ++kt) {
            const int chunk = (kt * 64 + q * 16) ^ ((cl & 7) << 4);
            const f16x8 af = *(const f16x8*)(hb + cl * 256 + chunk);
            dacc = __builtin_amdgcn_mfma_f32_16x16x32_f16(af, Wf[kt], dacc, 0, 0, 0);
        }
        #pragma unroll
        for (int i = 0; i < 4; ++i) {
            const float v = dacc[i];
            const float sw = v * frcp_(1.f + fexp2_(-LOG2E * v));
            *(float*)(&lds[DBUF_OFF + (4 * q + i) * 528 + col * 4]) = sw;
        }
    }
    __syncthreads();

    // ---- logits + softmax: wave 0, 48 lanes = 16 rows x 3 classes ----
    if (w == 0 && l < 48) {
        const int row = l & 15, ci = l >> 4;
        float acc = bout[ci];
        #pragma unroll 4
        for (int k = 0; k < D_; ++k)
            acc = fmaf(*(const float*)(&lds[DBUF_OFF + row * 528 + k * 4]),
                       Wout[k * 3 + ci], acc);
        const float v0 = __shfl(acc, row);
        const float v1 = __shfl(acc, row + 16);
        const float v2 = __shfl(acc, row + 32);
        const float mx = fmaxf(v0, fmaxf(v1, v2));
        const float e0 = fexp2_(LOG2E * (v0 - mx));
        const float e1 = fexp2_(LOG2E * (v1 - mx));
        const float e2 = fexp2_(LOG2E * (v2 - mx));
        const float inv = frcp_(e0 + e1 + e2);
        const float mine = (ci == 0) ? e0 : (ci == 1) ? e1 : e2;
        out[(size_t)(R0 + row) * 3 + ci] = mine * inv;
    }
}

extern "C" void kernel_launch(void* const* d_in, const int* in_sizes, int n_in,
                              void* d_out, int out_size, void* d_ws, size_t ws_size,
                              hipStream_t stream) {
    (void)in_sizes; (void)n_in; (void)out_size; (void)ws_size;
    const int*   tokens = (const int*)d_in[0];
    const float* emb    = (const float*)d_in[1];
    const float* W      = (const float*)d_in[2];
    const float* U      = (const float*)d_in[3];
    const float* b      = (const float*)d_in[4];
    const float* W1     = (const float*)d_in[5];
    const float* b1     = (const float*)d_in[6];
    const float* Wout   = (const float*)d_in[7];
    const float* bout   = (const float*)d_in[8];
    float* out  = (float*)d_out;
    f16*   embW = (f16*)d_ws;   // [V][128][4] f16 = 30.7 MB scratch

    hipLaunchKernelGGL(embw_kernel, dim3((V_ + K1_ROWS - 1) / K1_ROWS), dim3(384), 0, stream,
                       emb, W, b, embW);
    hipLaunchKernelGGL(gru_mfma_kernel, dim3(B_ / 16), dim3(512), 0, stream,
                       tokens, embW, U, b, W1, b1, Wout, bout, out);
}